// Round 1
// baseline (23.486 us; speedup 1.0000x reference)
//
#include <hip/hip_runtime.h>
#include <type_traits>

typedef float v2f __attribute__((ext_vector_type(2)));

// constant address space -> backend emits s_load (scalar pipe, SGPR return)
template <typename T>
using cptr = T __attribute__((address_space(4)))*;

constexpr int BLOCK = 256;          // 4 waves; each lane owns ONE sample, all 8 lags
constexpr int SPB = 256;            // samples per block (1 per lane)
constexpr int HALO_LO = 10;         // l_max(7) + m_max(3)
constexpr int HALO_HI = 3;          // +m_max for the c (leading) term
constexpr int SIG = SPB + HALO_LO + HALO_HI;   // 269

// ---------------- compile-time unroll helper ----------------
template<int I, int N, typename F>
__device__ __forceinline__ void unroll_for(F&& f) {
    if constexpr (I < N) {
        f(std::integral_constant<int, I>{});
        unroll_for<I + 1, N>(static_cast<F&&>(f));
    }
}

// ---------------- kernel 1: fold coefficients ----------------
// w[(l*7+s)*16 + 2k + {0,1}] = (re,im) of W[l][s][k].
// slot 0 = a[:,l] + b[:,l,0] + c[:,l,0]; slots 1..3 = b m=1..3; 4..6 = c m=1..3.
__global__ void prefold_kernel(
    const float* __restrict__ a_re, const float* __restrict__ a_im,
    const float* __restrict__ b_re, const float* __restrict__ b_im,
    const float* __restrict__ c_re, const float* __restrict__ c_im,
    float* __restrict__ w)
{
    int idx = threadIdx.x;
    if (idx >= 448) return;
    int l = idx / 56;
    int rem = idx - l * 56;
    int s = rem >> 3;
    int k = rem & 7;
    int akl = k * 8 + l;                   // a[k][l]; b/c[k][l][m] = akl*4 + m
    float re, im;
    if (s == 0) {
        re = a_re[akl] + b_re[akl * 4] + c_re[akl * 4];
        im = a_im[akl] + b_im[akl * 4] + c_im[akl * 4];
    } else if (s <= 3) {
        re = b_re[akl * 4 + s];
        im = b_im[akl * 4 + s];
    } else {
        re = c_re[akl * 4 + (s - 3)];
        im = c_im[akl * 4 + (s - 3)];
    }
    w[idx * 2]     = re;
    w[idx * 2 + 1] = im;
}

// ---------------- kernel 2: main GMP ----------------
// y[n] = sum_L x[n-L] * sum_s P_{L,s}(r[n-L+d(s)]),  d: 0,-1,-2,-3,+1,+2,+3
// One lane = one sample, all 8 lags (no cross-wave reduction).
// Coefficients via AS4 (s_load), uniform across the wave.
__global__ __launch_bounds__(BLOCK, 4) void gmp_kernel(
    const float* __restrict__ x,
    const float* __restrict__ wbuf,        // folded coefficients (896 floats)
    float* __restrict__ out, int N)
{
    __shared__ float2 sx[SIG];             // complex signal window
    __shared__ float sab[SIG];             // |x| window

    const int t = threadIdx.x;
    const int n0 = blockIdx.x * SPB;

    // ---- stage signal + envelope with clipped halo ----
    const float2* x2 = (const float2*)x;
    for (int j = t; j < SIG; j += BLOCK) {
        int g = n0 - HALO_LO + j;
        g = max(0, min(N - 1, g));
        float2 v = x2[g];
        sx[j] = v;
        sab[j] = __builtin_amdgcn_sqrtf(fmaf(v.x, v.x, v.y * v.y));
    }
    __syncthreads();

    // constant-AS view of the folded table (uniform base, compile-time offsets)
    auto cw = (cptr<const float>)(unsigned long long)wbuf;

    // windows into registers; all stride-1 LDS reads (conflict-free)
    // rv[i]  = |x[n-10+i]|, i = 0..13
    // xv[i]  =  x[n-7+i],   i = 0..7   (lag l uses i = 7-l)
    float rv[14];
    unroll_for<0, 14>([&](auto I) { rv[I.value] = sab[t + I.value]; });
    float xvr[8], xvi[8];
    unroll_for<0, 8>([&](auto I) {
        float2 v = sx[t + 3 + I.value];
        xvr[I.value] = v.x;
        xvi[I.value] = v.y;
    });

    float yr = 0.f, yi = 0.f;

    unroll_for<0, 8>([&](auto LL) {
        constexpr int l = LL.value;
        v2f S = {0.f, 0.f};
        unroll_for<0, 7>([&](auto Sc) {
            constexpr int s = Sc.value;
            constexpr int d = (s == 0) ? 0 : ((s <= 3) ? -s : (s - 3));
            constexpr int off = l * 112 + s * 16;
            // uniform scalar coefficient fetch (s_load from AS4)
            float cre[8], cim[8];
            unroll_for<0, 8>([&](auto K) {
                cre[K.value] = cw[off + 2 * K.value];
                cim[K.value] = cw[off + 2 * K.value + 1];
            });
            const float r = rv[10 - l + d];
            const v2f rr = {r, r};
            v2f acc = {cre[7], cim[7]};
            unroll_for<0, 7>([&](auto Kc) {
                constexpr int k = 6 - Kc.value;
                const v2f wk = {cre[k], cim[k]};
                acc = __builtin_elementwise_fma(acc, rr, wk);
            });
            S += acc;
        });
        const float xre = xvr[7 - l], xim = xvi[7 - l];
        yr = fmaf(xre, S.x, fmaf(-xim, S.y, yr));
        yi = fmaf(xre, S.y, fmaf( xim, S.x, yi));
    });

    const int n = n0 + t;
    if (n < N) ((float2*)out)[n] = make_float2(yr, yi);
}

extern "C" void kernel_launch(void* const* d_in, const int* in_sizes, int n_in,
                              void* d_out, int out_size, void* d_ws, size_t ws_size,
                              hipStream_t stream) {
    const float* x    = (const float*)d_in[0];
    const float* a_re = (const float*)d_in[1];
    const float* a_im = (const float*)d_in[2];
    const float* b_re = (const float*)d_in[3];
    const float* b_im = (const float*)d_in[4];
    const float* c_re = (const float*)d_in[5];
    const float* c_im = (const float*)d_in[6];
    float* out = (float*)d_out;
    float* w   = (float*)d_ws;             // 896 floats = 3584 bytes used

    int N = in_sizes[0] / 2;
    prefold_kernel<<<1, 448, 0, stream>>>(a_re, a_im, b_re, b_im, c_re, c_im, w);
    int grid = (N + SPB - 1) / SPB;        // 1024 blocks
    gmp_kernel<<<grid, BLOCK, 0, stream>>>(x, w, out, N);
}

// Round 2
// 16.680 us; speedup vs baseline: 1.4081x; 1.4081x over previous
//
#include <hip/hip_runtime.h>
#include <type_traits>

typedef float v2f __attribute__((ext_vector_type(2)));

// constant address space -> backend emits s_load (scalar pipe, SGPR return)
template <typename T>
using cptr = T __attribute__((address_space(4)))*;

constexpr int BLOCK = 256;          // 4 waves; wave w owns lags {2w, 2w+1}
constexpr int SPB = 256;            // samples per block (4 per lane)
constexpr int HALO_LO = 10;         // l_max(7) + m_max(3)
constexpr int HALO_HI = 3;          // +m_max for the c (leading) term
constexpr int SIG = SPB + HALO_LO + HALO_HI;   // 269

// ---------------- compile-time unroll helper ----------------
template<int I, int N, typename F>
__device__ __forceinline__ void unroll_for(F&& f) {
    if constexpr (I < N) {
        f(std::integral_constant<int, I>{});
        unroll_for<I + 1, N>(static_cast<F&&>(f));
    }
}

// ---------------- kernel 1: fold coefficients ----------------
// w[(l*7+s)*16 + 2k + {0,1}] = (re,im) of W[l][s][k].
// slot 0 = a[:,l] + b[:,l,0] + c[:,l,0]; slots 1..3 = b m=1..3; 4..6 = c m=1..3.
__global__ void prefold_kernel(
    const float* __restrict__ a_re, const float* __restrict__ a_im,
    const float* __restrict__ b_re, const float* __restrict__ b_im,
    const float* __restrict__ c_re, const float* __restrict__ c_im,
    float* __restrict__ w)
{
    int idx = threadIdx.x;
    if (idx >= 448) return;
    int l = idx / 56;
    int rem = idx - l * 56;
    int s = rem >> 3;
    int k = rem & 7;
    int akl = k * 8 + l;                   // a[k][l]; b/c[k][l][m] = akl*4 + m
    float re, im;
    if (s == 0) {
        re = a_re[akl] + b_re[akl * 4] + c_re[akl * 4];
        im = a_im[akl] + b_im[akl * 4] + c_im[akl * 4];
    } else if (s <= 3) {
        re = b_re[akl * 4 + s];
        im = b_im[akl * 4 + s];
    } else {
        re = c_re[akl * 4 + (s - 3)];
        im = c_im[akl * 4 + (s - 3)];
    }
    w[idx * 2]     = re;
    w[idx * 2 + 1] = im;
}

// ---------------- kernel 2: main GMP ----------------
// y[n] = sum_L x[n-L] * sum_s P_{L,s}(r[n-L+d(s)]),  d: 0,-1,-2,-3,+1,+2,+3
// Wave w: lags {2w, 2w+1}; lane: samples {4*s2 .. 4*s2+3}. Each scalar
// coefficient fetch feeds 4 independent Horner chains (ILP). Partials
// combined through LDS.
__global__ __launch_bounds__(BLOCK) void gmp_kernel(
    const float* __restrict__ x,
    const float* __restrict__ wbuf,        // folded coefficients (896 floats)
    float* __restrict__ out, int N)
{
    __shared__ float2 sx[SIG];             // complex signal window
    __shared__ float sab[SIG];             // |x| window
    __shared__ float2 part[4][4][64];      // [wave][q][lane] -> sample 4*lane+q

    const int t = threadIdx.x;
    const int n0 = blockIdx.x * SPB;

    // ---- stage signal + envelope with clipped halo ----
    const float2* x2 = (const float2*)x;
    for (int j = t; j < SIG; j += BLOCK) {
        int g = n0 - HALO_LO + j;
        g = max(0, min(N - 1, g));
        float2 v = x2[g];
        sx[j] = v;
        sab[j] = __builtin_amdgcn_sqrtf(fmaf(v.x, v.x, v.y * v.y));
    }
    __syncthreads();

    const int s2 = t & 63;                                   // sample lane
    const int wv = __builtin_amdgcn_readfirstlane(t >> 6);   // wave id 0..3
    // constant-AS view of this wave's 14 slots (uniform base)
    auto cw = (cptr<const float>)(unsigned long long)(wbuf + wv * 224);

    const int nb = 4 * s2;                 // first block-local sample of lane
    // envelope window: rv[i] = sab[nb + 6 - 2w + i]; slot (ll,d,q) uses
    // rv[q - ll + d + 4], range [0,10]
    const int rb = nb + 6 - 2 * wv;
    float rv[11];
    unroll_for<0, 11>([&](auto I) { rv[I.value] = sab[rb + I.value]; });
    // signal window: xv[j] = sx[nb + 9 - 2w + j]; lag ll, sample q uses
    // xv[q - ll + 1], range [0,4]
    float xvr[5], xvi[5];
    unroll_for<0, 5>([&](auto I) {
        float2 v = sx[nb + 9 - 2 * wv + I.value];
        xvr[I.value] = v.x;
        xvi[I.value] = v.y;
    });

    float yr[4] = {0.f, 0.f, 0.f, 0.f};
    float yi[4] = {0.f, 0.f, 0.f, 0.f};

    unroll_for<0, 2>([&](auto LL) {
        constexpr int ll = LL.value;       // local lag: L = 2*wv + ll
        v2f S[4] = {{0.f,0.f},{0.f,0.f},{0.f,0.f},{0.f,0.f}};
        unroll_for<0, 7>([&](auto Sc) {
            constexpr int s = Sc.value;
            constexpr int d = (s == 0) ? 0 : ((s <= 3) ? -s : (s - 3));
            constexpr int off = ll * 112 + s * 16;
            // uniform scalar coefficient fetch (s_load from AS4)
            float cre[8], cim[8];
            unroll_for<0, 8>([&](auto K) {
                cre[K.value] = cw[off + 2 * K.value];
                cim[K.value] = cw[off + 2 * K.value + 1];
            });
            v2f acc[4];
            unroll_for<0, 4>([&](auto Q) { acc[Q.value] = (v2f){cre[7], cim[7]}; });
            unroll_for<0, 7>([&](auto Kc) {
                constexpr int k = 6 - Kc.value;
                const v2f wk = {cre[k], cim[k]};
                unroll_for<0, 4>([&](auto Q) {
                    constexpr int q = Q.value;
                    const float r = rv[q - ll + d + 4];
                    acc[q] = __builtin_elementwise_fma(acc[q], (v2f){r, r}, wk);
                });
            });
            unroll_for<0, 4>([&](auto Q) { S[Q.value] += acc[Q.value]; });
        });
        unroll_for<0, 4>([&](auto Q) {
            constexpr int q = Q.value;
            const float xre = xvr[q - ll + 1], xim = xvi[q - ll + 1];
            yr[q] = fmaf(xre, S[q].x, fmaf(-xim, S[q].y, yr[q]));
            yi[q] = fmaf(xre, S[q].y, fmaf( xim, S[q].x, yi[q]));
        });
    });

    // conflict-free partial writes: stride-8B within each [wv][q] row
    unroll_for<0, 4>([&](auto Q) {
        part[wv][Q.value][s2] = make_float2(yr[Q.value], yi[Q.value]);
    });
    __syncthreads();

    // all 256 lanes reduce one sample each
    {
        const int q = t & 3, lane = t >> 2;
        float2 p0 = part[0][q][lane];
        float2 p1 = part[1][q][lane];
        float2 p2 = part[2][q][lane];
        float2 p3 = part[3][q][lane];
        float2 r;
        r.x = (p0.x + p1.x) + (p2.x + p3.x);
        r.y = (p0.y + p1.y) + (p2.y + p3.y);
        const int n = n0 + t;
        if (n < N) ((float2*)out)[n] = r;
    }
}

extern "C" void kernel_launch(void* const* d_in, const int* in_sizes, int n_in,
                              void* d_out, int out_size, void* d_ws, size_t ws_size,
                              hipStream_t stream) {
    const float* x    = (const float*)d_in[0];
    const float* a_re = (const float*)d_in[1];
    const float* a_im = (const float*)d_in[2];
    const float* b_re = (const float*)d_in[3];
    const float* b_im = (const float*)d_in[4];
    const float* c_re = (const float*)d_in[5];
    const float* c_im = (const float*)d_in[6];
    float* out = (float*)d_out;
    float* w   = (float*)d_ws;             // 896 floats = 3584 bytes used

    int N = in_sizes[0] / 2;
    prefold_kernel<<<1, 448, 0, stream>>>(a_re, a_im, b_re, b_im, c_re, c_im, w);
    int grid = (N + SPB - 1) / SPB;        // 1024 blocks
    gmp_kernel<<<grid, BLOCK, 0, stream>>>(x, w, out, N);
}

// Round 3
// 15.356 us; speedup vs baseline: 1.5295x; 1.0862x over previous
//
#include <hip/hip_runtime.h>
#include <type_traits>

typedef float v2f __attribute__((ext_vector_type(2)));

// constant address space -> backend emits s_load (scalar pipe, SGPR return)
template <typename T>
using cptr = T __attribute__((address_space(4)))*;

constexpr int BLOCK = 256;          // 4 waves; wave w owns lags {2w, 2w+1}
constexpr int SPB = 128;            // samples per block (2 per lane)
constexpr int HALO_LO = 10;         // l_max(7) + m_max(3)
constexpr int HALO_HI = 3;          // +m_max for the c (leading) term
constexpr int SIG = SPB + HALO_LO + HALO_HI;   // 141

// ---------------- compile-time unroll helper ----------------
template<int I, int N, typename F>
__device__ __forceinline__ void unroll_for(F&& f) {
    if constexpr (I < N) {
        f(std::integral_constant<int, I>{});
        unroll_for<I + 1, N>(static_cast<F&&>(f));
    }
}

// ---------------- kernel 1: fold coefficients ----------------
// w[(l*7+s)*16 + 2k + {0,1}] = (re,im) of W[l][s][k].
// slot 0 = a[:,l] + b[:,l,0] + c[:,l,0]; slots 1..3 = b m=1..3; 4..6 = c m=1..3.
__global__ void prefold_kernel(
    const float* __restrict__ a_re, const float* __restrict__ a_im,
    const float* __restrict__ b_re, const float* __restrict__ b_im,
    const float* __restrict__ c_re, const float* __restrict__ c_im,
    float* __restrict__ w)
{
    int idx = threadIdx.x;
    if (idx >= 448) return;
    int l = idx / 56;
    int rem = idx - l * 56;
    int s = rem >> 3;
    int k = rem & 7;
    int akl = k * 8 + l;                   // a[k][l]; b/c[k][l][m] = akl*4 + m
    float re, im;
    if (s == 0) {
        re = a_re[akl] + b_re[akl * 4] + c_re[akl * 4];
        im = a_im[akl] + b_im[akl * 4] + c_im[akl * 4];
    } else if (s <= 3) {
        re = b_re[akl * 4 + s];
        im = b_im[akl * 4 + s];
    } else {
        re = c_re[akl * 4 + (s - 3)];
        im = c_im[akl * 4 + (s - 3)];
    }
    w[idx * 2]     = re;
    w[idx * 2 + 1] = im;
}

// ---------------- kernel 2: main GMP ----------------
// y[n] = sum_L x[n-L] * sum_s P_{L,s}(r[n-L+d(s)]),  d: 0,-1,-2,-3,+1,+2,+3
// Wave w: lags {2w, 2w+1}; lane: samples {2*s2, 2*s2+1}. Coefficients via
// AS4 (s_load). Partials combined through LDS.
// __launch_bounds__(256, 8): force VGPR<=64 so 8 blocks/CU stay resident
// (32 waves/CU) -- the kernel is stall-bound, residency is the hiding lever.
__global__ __launch_bounds__(BLOCK, 8) void gmp_kernel(
    const float* __restrict__ x,
    const float* __restrict__ wbuf,        // folded coefficients (896 floats)
    float* __restrict__ out, int N)
{
    __shared__ float2 sx[SIG];             // complex signal window
    __shared__ float sab[SIG];             // |x| window
    __shared__ float2 part[4][SPB];

    const int t = threadIdx.x;
    const int n0 = blockIdx.x * SPB;

    // ---- stage signal + envelope with clipped halo (single predicated pass) ----
    const float2* x2 = (const float2*)x;
    if (t < SIG) {
        int g = n0 - HALO_LO + t;
        g = max(0, min(N - 1, g));
        float2 v = x2[g];
        sx[t] = v;
        sab[t] = __builtin_amdgcn_sqrtf(fmaf(v.x, v.x, v.y * v.y));
    }
    __syncthreads();

    const int s2 = t & 63;                                   // sample lane
    const int wv = __builtin_amdgcn_readfirstlane(t >> 6);   // wave id 0..3
    // constant-AS view of this wave's 14 slots (uniform base)
    auto cw = (cptr<const float>)(unsigned long long)(wbuf + wv * 224);

    // window: rv[i] = |x| at smem index rb + i, i = 0..8
    const int rb = 2 * s2 + 6 - 2 * wv;
    float rv[9];
    unroll_for<0, 9>([&](auto I) { rv[I.value] = sab[rb + I.value]; });
    float xvr[3], xvi[3];          // x at smem index rb + 3 + i
    unroll_for<0, 3>([&](auto I) {
        float2 v = sx[rb + 3 + I.value];
        xvr[I.value] = v.x;
        xvi[I.value] = v.y;
    });

    float y0r = 0.f, y0i = 0.f, y1r = 0.f, y1i = 0.f;

    unroll_for<0, 2>([&](auto LL) {
        constexpr int ll = LL.value;       // local lag: L = 2*wv + ll
        v2f S0 = {0.f, 0.f}, S1 = {0.f, 0.f};
        unroll_for<0, 7>([&](auto Sc) {
            constexpr int s = Sc.value;
            constexpr int d = (s == 0) ? 0 : ((s <= 3) ? -s : (s - 3));
            constexpr int off = ll * 112 + s * 16;
            // uniform scalar coefficient fetch (s_load from AS4)
            float cre[8], cim[8];
            unroll_for<0, 8>([&](auto K) {
                cre[K.value] = cw[off + 2 * K.value];
                cim[K.value] = cw[off + 2 * K.value + 1];
            });
            const float r0 = rv[4 - ll + d];       // sample q=0
            const float r1 = rv[5 - ll + d];       // sample q=1
            const v2f rr0 = {r0, r0};
            const v2f rr1 = {r1, r1};
            v2f acc0 = {cre[7], cim[7]};
            v2f acc1 = acc0;
            unroll_for<0, 7>([&](auto Kc) {
                constexpr int k = 6 - Kc.value;
                const v2f wk = {cre[k], cim[k]};
                acc0 = __builtin_elementwise_fma(acc0, rr0, wk);
                acc1 = __builtin_elementwise_fma(acc1, rr1, wk);
            });
            S0 += acc0;
            S1 += acc1;
        });
        {
            const float xre = xvr[1 - ll], xim = xvi[1 - ll];
            y0r = fmaf(xre, S0.x, fmaf(-xim, S0.y, y0r));
            y0i = fmaf(xre, S0.y, fmaf( xim, S0.x, y0i));
        }
        {
            const float xre = xvr[2 - ll], xim = xvi[2 - ll];
            y1r = fmaf(xre, S1.x, fmaf(-xim, S1.y, y1r));
            y1i = fmaf(xre, S1.y, fmaf( xim, S1.x, y1i));
        }
    });

    part[wv][2 * s2]     = make_float2(y0r, y0i);
    part[wv][2 * s2 + 1] = make_float2(y1r, y1i);
    __syncthreads();

    if (t < SPB) {
        float2 p0 = part[0][t];
        float2 p1 = part[1][t];
        float2 p2 = part[2][t];
        float2 p3 = part[3][t];
        float2 r;
        r.x = (p0.x + p1.x) + (p2.x + p3.x);
        r.y = (p0.y + p1.y) + (p2.y + p3.y);
        const int n = n0 + t;
        if (n < N) ((float2*)out)[n] = r;
    }
}

extern "C" void kernel_launch(void* const* d_in, const int* in_sizes, int n_in,
                              void* d_out, int out_size, void* d_ws, size_t ws_size,
                              hipStream_t stream) {
    const float* x    = (const float*)d_in[0];
    const float* a_re = (const float*)d_in[1];
    const float* a_im = (const float*)d_in[2];
    const float* b_re = (const float*)d_in[3];
    const float* b_im = (const float*)d_in[4];
    const float* c_re = (const float*)d_in[5];
    const float* c_im = (const float*)d_in[6];
    float* out = (float*)d_out;
    float* w   = (float*)d_ws;             // 896 floats = 3584 bytes used

    int N = in_sizes[0] / 2;
    prefold_kernel<<<1, 448, 0, stream>>>(a_re, a_im, b_re, b_im, c_re, c_im, w);
    int grid = (N + SPB - 1) / SPB;        // 2048 blocks
    gmp_kernel<<<grid, BLOCK, 0, stream>>>(x, w, out, N);
}

// Round 4
// 14.037 us; speedup vs baseline: 1.6732x; 1.0940x over previous
//
#include <hip/hip_runtime.h>
#include <type_traits>

typedef float v2f __attribute__((ext_vector_type(2)));

constexpr int BLOCK = 256;          // 4 waves; wave w owns lags {2w, 2w+1}
constexpr int SPB = 128;            // samples per block (2 per lane)
constexpr int HALO_LO = 10;         // l_max(7) + m_max(3)
constexpr int HALO_HI = 3;          // +m_max for the c (leading) term
constexpr int SIG = SPB + HALO_LO + HALO_HI;   // 141

// ---------------- compile-time unroll helper ----------------
template<int I, int N, typename F>
__device__ __forceinline__ void unroll_for(F&& f) {
    if constexpr (I < N) {
        f(std::integral_constant<int, I>{});
        unroll_for<I + 1, N>(static_cast<F&&>(f));
    }
}

// ---------------- single fused kernel ----------------
// y[n] = sum_L x[n-L] * sum_s P_{L,s}(r[n-L+d(s)]),  d: 0,-1,-2,-3,+1,+2,+3
// Every block folds the coefficient tables into LDS itself (3.6 KB of
// inputs, L1/L2-hot after the first blocks) -- removes the serialized
// prefold kernel launch. Coefficient reads in the inner loop are
// wave-uniform LDS addresses -> broadcast, conflict-free.
// wlds[(l*7+s)*16 + 2k + {0,1}] = (re,im) of W[l][s][k].
// slot 0 = a[:,l] + b[:,l,0] + c[:,l,0]; slots 1..3 = b m=1..3; 4..6 = c m=1..3.
__global__ __launch_bounds__(BLOCK) void gmp_kernel(
    const float* __restrict__ x,
    const float* __restrict__ a_re, const float* __restrict__ a_im,
    const float* __restrict__ b_re, const float* __restrict__ b_im,
    const float* __restrict__ c_re, const float* __restrict__ c_im,
    float* __restrict__ out, int N)
{
    __shared__ float2 sx[SIG];             // complex signal window
    __shared__ float sab[SIG];             // |x| window
    __shared__ float2 part[4][SPB];
    __shared__ __align__(16) float wlds[896];   // folded coefficients

    const int t = threadIdx.x;
    const int n0 = blockIdx.x * SPB;

    // ---- stage signal + envelope with clipped halo (single predicated pass) ----
    const float2* x2 = (const float2*)x;
    if (t < SIG) {
        int g = n0 - HALO_LO + t;
        g = max(0, min(N - 1, g));
        float2 v = x2[g];
        sx[t] = v;
        sab[t] = __builtin_amdgcn_sqrtf(fmaf(v.x, v.x, v.y * v.y));
    }

    // ---- fold coefficients into LDS (overlaps halo staging) ----
    for (int idx = t; idx < 448; idx += BLOCK) {
        int l = idx / 56;
        int rem = idx - l * 56;
        int s = rem >> 3;
        int k = rem & 7;
        int akl = k * 8 + l;               // a[k][l]; b/c[k][l][m] = akl*4 + m
        float re, im;
        if (s == 0) {
            re = a_re[akl] + b_re[akl * 4] + c_re[akl * 4];
            im = a_im[akl] + b_im[akl * 4] + c_im[akl * 4];
        } else if (s <= 3) {
            re = b_re[akl * 4 + s];
            im = b_im[akl * 4 + s];
        } else {
            re = c_re[akl * 4 + (s - 3)];
            im = c_im[akl * 4 + (s - 3)];
        }
        wlds[idx * 2]     = re;
        wlds[idx * 2 + 1] = im;
    }
    __syncthreads();

    const int s2 = t & 63;                                   // sample lane
    const int wv = __builtin_amdgcn_readfirstlane(t >> 6);   // wave id 0..3
    const float* cw = &wlds[wv * 224];     // this wave's 14 slots (uniform base)

    // window: rv[i] = |x| at smem index rb + i, i = 0..8
    const int rb = 2 * s2 + 6 - 2 * wv;
    float rv[9];
    unroll_for<0, 9>([&](auto I) { rv[I.value] = sab[rb + I.value]; });
    float xvr[3], xvi[3];          // x at smem index rb + 3 + i
    unroll_for<0, 3>([&](auto I) {
        float2 v = sx[rb + 3 + I.value];
        xvr[I.value] = v.x;
        xvi[I.value] = v.y;
    });

    float y0r = 0.f, y0i = 0.f, y1r = 0.f, y1i = 0.f;

    unroll_for<0, 2>([&](auto LL) {
        constexpr int ll = LL.value;       // local lag: L = 2*wv + ll
        v2f S0 = {0.f, 0.f}, S1 = {0.f, 0.f};
        unroll_for<0, 7>([&](auto Sc) {
            constexpr int s = Sc.value;
            constexpr int d = (s == 0) ? 0 : ((s <= 3) ? -s : (s - 3));
            constexpr int off = ll * 112 + s * 16;
            // wave-uniform coefficient fetch from LDS (broadcast ds_read)
            v2f wk[8];
            unroll_for<0, 8>([&](auto K) {
                wk[K.value] = *(const v2f*)&cw[off + 2 * K.value];
            });
            const float r0 = rv[4 - ll + d];       // sample q=0
            const float r1 = rv[5 - ll + d];       // sample q=1
            const v2f rr0 = {r0, r0};
            const v2f rr1 = {r1, r1};
            v2f acc0 = wk[7];
            v2f acc1 = acc0;
            unroll_for<0, 7>([&](auto Kc) {
                constexpr int k = 6 - Kc.value;
                acc0 = __builtin_elementwise_fma(acc0, rr0, wk[k]);
                acc1 = __builtin_elementwise_fma(acc1, rr1, wk[k]);
            });
            S0 += acc0;
            S1 += acc1;
        });
        {
            const float xre = xvr[1 - ll], xim = xvi[1 - ll];
            y0r = fmaf(xre, S0.x, fmaf(-xim, S0.y, y0r));
            y0i = fmaf(xre, S0.y, fmaf( xim, S0.x, y0i));
        }
        {
            const float xre = xvr[2 - ll], xim = xvi[2 - ll];
            y1r = fmaf(xre, S1.x, fmaf(-xim, S1.y, y1r));
            y1i = fmaf(xre, S1.y, fmaf( xim, S1.x, y1i));
        }
    });

    part[wv][2 * s2]     = make_float2(y0r, y0i);
    part[wv][2 * s2 + 1] = make_float2(y1r, y1i);
    __syncthreads();

    if (t < SPB) {
        float2 p0 = part[0][t];
        float2 p1 = part[1][t];
        float2 p2 = part[2][t];
        float2 p3 = part[3][t];
        float2 r;
        r.x = (p0.x + p1.x) + (p2.x + p3.x);
        r.y = (p0.y + p1.y) + (p2.y + p3.y);
        const int n = n0 + t;
        if (n < N) ((float2*)out)[n] = r;
    }
}

extern "C" void kernel_launch(void* const* d_in, const int* in_sizes, int n_in,
                              void* d_out, int out_size, void* d_ws, size_t ws_size,
                              hipStream_t stream) {
    const float* x    = (const float*)d_in[0];
    const float* a_re = (const float*)d_in[1];
    const float* a_im = (const float*)d_in[2];
    const float* b_re = (const float*)d_in[3];
    const float* b_im = (const float*)d_in[4];
    const float* c_re = (const float*)d_in[5];
    const float* c_im = (const float*)d_in[6];
    float* out = (float*)d_out;

    int N = in_sizes[0] / 2;
    int grid = (N + SPB - 1) / SPB;        // 2048 blocks
    gmp_kernel<<<grid, BLOCK, 0, stream>>>(x, a_re, a_im, b_re, b_im,
                                           c_re, c_im, out, N);
}

// Round 5
// 13.002 us; speedup vs baseline: 1.8063x; 1.0796x over previous
//
#include <hip/hip_runtime.h>
#include <type_traits>

typedef float v2f __attribute__((ext_vector_type(2)));

constexpr int BLOCK = 256;          // 4 waves; wave w owns lags {2w, 2w+1}
constexpr int SPB = 256;            // samples per block (4 per lane)
constexpr int HALO_LO = 10;         // l_max(7) + m_max(3)
constexpr int HALO_HI = 3;          // +m_max for the c (leading) term
constexpr int SIG = SPB + HALO_LO + HALO_HI;   // 269

// ---------------- compile-time unroll helper ----------------
template<int I, int N, typename F>
__device__ __forceinline__ void unroll_for(F&& f) {
    if constexpr (I < N) {
        f(std::integral_constant<int, I>{});
        unroll_for<I + 1, N>(static_cast<F&&>(f));
    }
}

// ---------------- single fused kernel ----------------
// y[n] = sum_L x[n-L] * sum_s P_{L,s}(r[n-L+d(s)]),  d: 0,-1,-2,-3,+1,+2,+3
// Wave w: lags {2w, 2w+1}; lane: samples {4*s2 .. 4*s2+3}. Coefficients are
// folded into LDS by every block (3.6 KB, L1/L2-hot); each wave-uniform
// coefficient broadcast is amortized over 4 samples/lane -- the kernel is
// LDS-return-bandwidth bound on these broadcasts, so bytes/sample is the
// lever (R4: 2 samples/lane = 56 B/sample -> here 28 B/sample).
// wlds[(l*7+s)*16 + 2k + {0,1}] = (re,im) of W[l][s][k].
// slot 0 = a[:,l] + b[:,l,0] + c[:,l,0]; slots 1..3 = b m=1..3; 4..6 = c m=1..3.
__global__ __launch_bounds__(BLOCK) void gmp_kernel(
    const float* __restrict__ x,
    const float* __restrict__ a_re, const float* __restrict__ a_im,
    const float* __restrict__ b_re, const float* __restrict__ b_im,
    const float* __restrict__ c_re, const float* __restrict__ c_im,
    float* __restrict__ out, int N)
{
    __shared__ float2 sx[SIG];             // complex signal window
    __shared__ float sab[SIG];             // |x| window
    __shared__ float2 part[4][4][64];      // [wave][q][lane] -> sample 4*lane+q
    __shared__ __align__(16) float wlds[896];   // folded coefficients

    const int t = threadIdx.x;
    const int n0 = blockIdx.x * SPB;

    // ---- stage signal + envelope with clipped halo ----
    const float2* x2 = (const float2*)x;
    for (int j = t; j < SIG; j += BLOCK) {
        int g = n0 - HALO_LO + j;
        g = max(0, min(N - 1, g));
        float2 v = x2[g];
        sx[j] = v;
        sab[j] = __builtin_amdgcn_sqrtf(fmaf(v.x, v.x, v.y * v.y));
    }

    // ---- fold coefficients into LDS (overlaps halo staging) ----
    for (int idx = t; idx < 448; idx += BLOCK) {
        int l = idx / 56;
        int rem = idx - l * 56;
        int s = rem >> 3;
        int k = rem & 7;
        int akl = k * 8 + l;               // a[k][l]; b/c[k][l][m] = akl*4 + m
        float re, im;
        if (s == 0) {
            re = a_re[akl] + b_re[akl * 4] + c_re[akl * 4];
            im = a_im[akl] + b_im[akl * 4] + c_im[akl * 4];
        } else if (s <= 3) {
            re = b_re[akl * 4 + s];
            im = b_im[akl * 4 + s];
        } else {
            re = c_re[akl * 4 + (s - 3)];
            im = c_im[akl * 4 + (s - 3)];
        }
        wlds[idx * 2]     = re;
        wlds[idx * 2 + 1] = im;
    }
    __syncthreads();

    const int s2 = t & 63;                                   // sample lane
    const int wv = __builtin_amdgcn_readfirstlane(t >> 6);   // wave id 0..3
    const float* cw = &wlds[wv * 224];     // this wave's 14 slots (uniform base)

    const int nb = 4 * s2;                 // first block-local sample of lane
    // envelope window: rv[i] = sab[nb + 6 - 2w + i]; slot (ll,d,q) uses
    // rv[q - ll + d + 4], range [0,10]
    const int rb = nb + 6 - 2 * wv;
    float rv[11];
    unroll_for<0, 11>([&](auto I) { rv[I.value] = sab[rb + I.value]; });
    // signal window: xv[j] = sx[nb + 9 - 2w + j]; lag ll, sample q uses
    // xv[q - ll + 1], range [0,4]
    float xvr[5], xvi[5];
    unroll_for<0, 5>([&](auto I) {
        float2 v = sx[nb + 9 - 2 * wv + I.value];
        xvr[I.value] = v.x;
        xvi[I.value] = v.y;
    });

    float yr[4] = {0.f, 0.f, 0.f, 0.f};
    float yi[4] = {0.f, 0.f, 0.f, 0.f};

    unroll_for<0, 2>([&](auto LL) {
        constexpr int ll = LL.value;       // local lag: L = 2*wv + ll
        v2f S[4] = {{0.f,0.f},{0.f,0.f},{0.f,0.f},{0.f,0.f}};
        unroll_for<0, 7>([&](auto Sc) {
            constexpr int s = Sc.value;
            constexpr int d = (s == 0) ? 0 : ((s <= 3) ? -s : (s - 3));
            constexpr int off = ll * 112 + s * 16;
            // wave-uniform coefficient fetch from LDS (broadcast ds_read)
            v2f wk[8];
            unroll_for<0, 8>([&](auto K) {
                wk[K.value] = *(const v2f*)&cw[off + 2 * K.value];
            });
            v2f acc[4];
            unroll_for<0, 4>([&](auto Q) { acc[Q.value] = wk[7]; });
            unroll_for<0, 7>([&](auto Kc) {
                constexpr int k = 6 - Kc.value;
                unroll_for<0, 4>([&](auto Q) {
                    constexpr int q = Q.value;
                    const float r = rv[q - ll + d + 4];
                    acc[q] = __builtin_elementwise_fma(acc[q], (v2f){r, r}, wk[k]);
                });
            });
            unroll_for<0, 4>([&](auto Q) { S[Q.value] += acc[Q.value]; });
        });
        unroll_for<0, 4>([&](auto Q) {
            constexpr int q = Q.value;
            const float xre = xvr[q - ll + 1], xim = xvi[q - ll + 1];
            yr[q] = fmaf(xre, S[q].x, fmaf(-xim, S[q].y, yr[q]));
            yi[q] = fmaf(xre, S[q].y, fmaf( xim, S[q].x, yi[q]));
        });
    });

    // conflict-free partial writes: stride-8B within each [wv][q] row
    unroll_for<0, 4>([&](auto Q) {
        part[wv][Q.value][s2] = make_float2(yr[Q.value], yi[Q.value]);
    });
    __syncthreads();

    // all 256 lanes reduce one sample each
    {
        const int q = t & 3, lane = t >> 2;
        float2 p0 = part[0][q][lane];
        float2 p1 = part[1][q][lane];
        float2 p2 = part[2][q][lane];
        float2 p3 = part[3][q][lane];
        float2 r;
        r.x = (p0.x + p1.x) + (p2.x + p3.x);
        r.y = (p0.y + p1.y) + (p2.y + p3.y);
        const int n = n0 + t;
        if (n < N) ((float2*)out)[n] = r;
    }
}

extern "C" void kernel_launch(void* const* d_in, const int* in_sizes, int n_in,
                              void* d_out, int out_size, void* d_ws, size_t ws_size,
                              hipStream_t stream) {
    const float* x    = (const float*)d_in[0];
    const float* a_re = (const float*)d_in[1];
    const float* a_im = (const float*)d_in[2];
    const float* b_re = (const float*)d_in[3];
    const float* b_im = (const float*)d_in[4];
    const float* c_re = (const float*)d_in[5];
    const float* c_im = (const float*)d_in[6];
    float* out = (float*)d_out;

    int N = in_sizes[0] / 2;
    int grid = (N + SPB - 1) / SPB;        // 1024 blocks
    gmp_kernel<<<grid, BLOCK, 0, stream>>>(x, a_re, a_im, b_re, b_im,
                                           c_re, c_im, out, N);
}